// Round 3
// baseline (7723.617 us; speedup 1.0000x reference)
//
#include <hip/hip_runtime.h>

// ---------- types / helpers ----------
typedef __attribute__((ext_vector_type(8))) short short8;
typedef __attribute__((ext_vector_type(4))) float f32x4;
typedef __attribute__((ext_vector_type(4))) unsigned int u32x4;

__device__ __forceinline__ float bf2f(unsigned short s) {
  unsigned int v = ((unsigned int)s) << 16; float f; __builtin_memcpy(&f, &v, 4); return f;
}
__device__ __forceinline__ unsigned short f2bf(float f) {
  unsigned int u; __builtin_memcpy(&u, &f, 4);
  u += 0x7fffu + ((u >> 16) & 1u);   // RNE (finite values only here)
  return (unsigned short)(u >> 16);
}
__device__ __forceinline__ unsigned int pack2bf(float lo, float hi) {
  return (unsigned int)f2bf(lo) | ((unsigned int)f2bf(hi) << 16);
}
__device__ __forceinline__ u32x4 pack8bf(f32x4 a, f32x4 b) {
  u32x4 r;
  r[0] = pack2bf(a[0], a[1]);
  r[1] = pack2bf(a[2], a[3]);
  r[2] = pack2bf(b[0], b[1]);
  r[3] = pack2bf(b[2], b[3]);
  return r;
}

// ---------- constants ----------
#define LSEQ   4096
#define DMODEL 2048
#define DINNER 4096
#define NHEADS 64
#define PROJ_N 4416    // D_INNER + NHEADS + 2*D_STATE

// ---------- bf16 MFMA GEMM:  C[m][n] = sum_k A[m][k] * B[n][k] ----------
// A: M x K row-major (fp32 if A_F32 else bf16); B: nmax x K fp32 row-major.
// fp32 operands are converted to bf16 during LDS staging.
// 128x128 tile, BK=32, 256 thr (2x2 waves), 16x16x32 MFMA.
template <bool A_F32, bool OUT_BF16>
__global__ __launch_bounds__(256) void gemm_nt(
    const void* __restrict__ Ap,
    const float* __restrict__ B,
    void* __restrict__ Cp, int K, int ldc, int nmax) {
  __shared__ __attribute__((aligned(16))) unsigned short Asm[128 * 32];
  __shared__ __attribute__((aligned(16))) unsigned short Bsm[128 * 32];
  const int tid = threadIdx.x;
  const int m0 = blockIdx.y * 128;
  const int n0 = blockIdx.x * 128;
  const int wave = tid >> 6, lane = tid & 63;
  const int wm = (wave >> 1) * 64, wn = (wave & 1) * 64;
  const int quad = lane >> 4, l16 = lane & 15;
  const int rowL = tid >> 2;
  const int kk = (tid & 3) * 8;
  const long lK = K;

  int rb0 = n0 + rowL;      if (rb0 > nmax - 1) rb0 = nmax - 1;
  int rb1 = n0 + rowL + 64; if (rb1 > nmax - 1) rb1 = nmax - 1;

  f32x4 zero = {0.f, 0.f, 0.f, 0.f};
  f32x4 acc[4][4];
#pragma unroll
  for (int i = 0; i < 4; ++i)
#pragma unroll
    for (int j = 0; j < 4; ++j) acc[i][j] = zero;

  for (int kt = 0; kt < K; kt += 32) {
    // B staging: fp32 -> bf16
    const float* pb0 = B + (long)rb0 * lK + kt + kk;
    const float* pb1 = B + (long)rb1 * lK + kt + kk;
    f32x4 b00 = *(const f32x4*)pb0;
    f32x4 b01 = *(const f32x4*)(pb0 + 4);
    f32x4 b10 = *(const f32x4*)pb1;
    f32x4 b11 = *(const f32x4*)(pb1 + 4);
    u32x4 bw0 = pack8bf(b00, b01);
    u32x4 bw1 = pack8bf(b10, b11);
    u32x4 aw0, aw1;
    if (A_F32) {
      const float* pa = (const float*)Ap + (long)(m0 + rowL) * lK + kt + kk;
      f32x4 a00 = *(const f32x4*)pa;
      f32x4 a01 = *(const f32x4*)(pa + 4);
      f32x4 a10 = *(const f32x4*)(pa + 64 * lK);
      f32x4 a11 = *(const f32x4*)(pa + 64 * lK + 4);
      aw0 = pack8bf(a00, a01);
      aw1 = pack8bf(a10, a11);
    } else {
      const unsigned short* pa = (const unsigned short*)Ap + (long)(m0 + rowL) * lK + kt + kk;
      aw0 = *(const u32x4*)pa;
      aw1 = *(const u32x4*)(pa + 64 * lK);
    }
    *(u32x4*)(Asm + tid * 8) = aw0;
    *(u32x4*)(Asm + tid * 8 + 2048) = aw1;
    *(u32x4*)(Bsm + tid * 8) = bw0;
    *(u32x4*)(Bsm + tid * 8 + 2048) = bw1;
    __syncthreads();
    short8 af[4], bfv[4];
#pragma unroll
    for (int i = 0; i < 4; ++i) {
      af[i]  = *(const short8*)(Asm + (wm + i * 16 + l16) * 32 + quad * 8);
      bfv[i] = *(const short8*)(Bsm + (wn + i * 16 + l16) * 32 + quad * 8);
    }
#pragma unroll
    for (int i = 0; i < 4; ++i)
#pragma unroll
      for (int j = 0; j < 4; ++j)
        acc[i][j] = __builtin_amdgcn_mfma_f32_16x16x32_bf16(af[i], bfv[j], acc[i][j], 0, 0, 0);
    __syncthreads();
  }

#pragma unroll
  for (int i = 0; i < 4; ++i) {
    const int mbase = m0 + wm + i * 16 + quad * 4;
#pragma unroll
    for (int j = 0; j < 4; ++j) {
      const int n = n0 + wn + j * 16 + l16;
      if (n < nmax) {
#pragma unroll
        for (int r = 0; r < 4; ++r) {
          const long o = (long)(mbase + r) * ldc + n;
          if (OUT_BF16) ((unsigned short*)Cp)[o] = f2bf(acc[i][j][r]);
          else          ((float*)Cp)[o] = acc[i][j][r];
        }
      }
    }
  }
}

// ---------- depthwise causal conv (taps=4) + bias + silu (bf16 in/out) ----------
__global__ void conv_silu_kernel(const unsigned short* __restrict__ xin,
                                 const float* __restrict__ cw,
                                 const float* __restrict__ cb,
                                 unsigned short* __restrict__ xout, long n) {
  long idx = (long)blockIdx.x * blockDim.x + threadIdx.x; // rows*4096
  if (idx >= n) return;
  int ch = (int)(idx & 4095);
  long row = idx >> 12;
  int l = (int)(row & (LSEQ - 1));
  float acc = cb[ch];
#pragma unroll
  for (int t = 0; t < 4; ++t) {
    int ll = l - 3 + t;
    float xv = (ll >= 0) ? bf2f(xin[(row - 3 + t) * 4096 + ch]) : 0.f;
    acc += xv * cw[ch * 4 + t];
  }
  acc = acc / (1.f + expf(-acc));
  xout[idx] = f2bf(acc);
}

// ---------- dt: softplus(dt_in @ dtW^T + dtb) -> fp32 ----------
__global__ void dt_kernel(const unsigned short* __restrict__ proj,
                          const float* __restrict__ dtw,
                          const float* __restrict__ dtb,
                          float* __restrict__ dt, long n) {
  long idx = (long)blockIdx.x * blockDim.x + threadIdx.x; // rows*64
  if (idx >= n) return;
  int h = (int)(idx & 63);
  long row = idx >> 6;
  const unsigned short* p = proj + row * PROJ_N + DINNER;
  float s = dtb[h];
#pragma unroll 8
  for (int k = 0; k < 64; ++k) s += bf2f(p[k]) * dtw[h * 64 + k];
  dt[idx] = (s > 20.f) ? s : log1pf(expf(s));
}

// ---------- SSD chunked scan + fused D-residual + silu(z) gating ----------
// one block per (seq_local, h); sequential over 64 chunks of 64 tokens.
// writes gated output IN PLACE over zio.
__global__ __launch_bounds__(512) void ssd_gate_kernel(
    const unsigned short* __restrict__ proj,  // rows x PROJ_N bf16
    const float* __restrict__ dtbuf,          // rows x 64
    const float* __restrict__ A_log,          // 64 fp32
    const float* __restrict__ Dv,             // 64 fp32
    unsigned short* __restrict__ zio) {       // rows x 4096 bf16, in/out
  __shared__ float st[64][128];   // state[p][n]
  __shared__ float Bs[64][128];   // B[j][n]
  __shared__ float Cs[64][128];   // C[i][n]
  __shared__ float Xs[64][64];    // X*dt [j][p]
  __shared__ float Sc[64][64];    // scores [i][j]
  __shared__ float cs[64];
  __shared__ float dtc[64];

  const int tid = threadIdx.x;
  const int bl = blockIdx.x >> 6;
  const int h = blockIdx.x & 63;
  const float negA = -expf(A_log[h]);
  const float Dh = Dv[h];

  for (int i = tid; i < 64 * 128; i += 512) (&st[0][0])[i] = 0.f;

  for (int c = 0; c < 64; ++c) {
    const long rowbase = (long)bl * LSEQ + c * 64;
    if (tid < 64) dtc[tid] = dtbuf[(rowbase + tid) * 64 + h];
    __syncthreads();
    if (tid == 0) {
      float run = 0.f;
      for (int j = 0; j < 64; ++j) { run += negA * dtc[j]; cs[j] = run; }
    }
    {
      const int j = tid >> 3;
      const int c8 = tid & 7;
      const unsigned short* rp = proj + (rowbase + j) * PROJ_N;
      const float dj = dtc[j];
#pragma unroll
      for (int q = 0; q < 8; ++q)
        Xs[j][c8 * 8 + q] = bf2f(rp[h * 64 + c8 * 8 + q]) * dj;
#pragma unroll
      for (int q = 0; q < 16; ++q) {
        Bs[j][c8 * 16 + q] = bf2f(rp[4160 + c8 * 16 + q]);
        Cs[j][c8 * 16 + q] = bf2f(rp[4288 + c8 * 16 + q]);
      }
    }
    __syncthreads();
    // scores: Sc[i][j] = (C_i . B_j) * exp(cs_i - cs_j), j<=i else 0
    {
      const int i0 = (tid >> 4) * 2;
      const int j0 = (tid & 15) * 4;
      float a[2][4] = {};
      for (int n = 0; n < 128; ++n) {
        float c0 = Cs[i0][n], c1 = Cs[i0 + 1][n];
        float b0 = Bs[j0][n], b1 = Bs[j0 + 1][n], b2 = Bs[j0 + 2][n], b3 = Bs[j0 + 3][n];
        a[0][0] += c0 * b0; a[0][1] += c0 * b1; a[0][2] += c0 * b2; a[0][3] += c0 * b3;
        a[1][0] += c1 * b0; a[1][1] += c1 * b1; a[1][2] += c1 * b2; a[1][3] += c1 * b3;
      }
#pragma unroll
      for (int ii = 0; ii < 2; ++ii)
#pragma unroll
        for (int jj = 0; jj < 4; ++jj) {
          int i = i0 + ii, j = j0 + jj;
          Sc[i][j] = (j <= i) ? a[ii][jj] * expf(cs[i] - cs[j]) : 0.f;
        }
    }
    __syncthreads();
    // Y[i][p] = sum_j Sc[i][j]*Xs[j][p] + exp(cs_i)*sum_n Cs[i][n]*st[p][n]
    // then gated output = (Y + X*D[h]) * silu(z), written over zio
    {
      const int i0 = (tid >> 4) * 2;
      const int p0 = (tid & 15) * 4;
      float a1[2][4] = {};
      for (int j = 0; j < 64; ++j) {
        float s0 = Sc[i0][j], s1 = Sc[i0 + 1][j];
        float x0 = Xs[j][p0], x1 = Xs[j][p0 + 1], x2 = Xs[j][p0 + 2], x3 = Xs[j][p0 + 3];
        a1[0][0] += s0 * x0; a1[0][1] += s0 * x1; a1[0][2] += s0 * x2; a1[0][3] += s0 * x3;
        a1[1][0] += s1 * x0; a1[1][1] += s1 * x1; a1[1][2] += s1 * x2; a1[1][3] += s1 * x3;
      }
      float a2[2][4] = {};
      for (int n = 0; n < 128; ++n) {
        float c0 = Cs[i0][n], c1 = Cs[i0 + 1][n];
        float t0 = st[p0][n], t1 = st[p0 + 1][n], t2 = st[p0 + 2][n], t3 = st[p0 + 3][n];
        a2[0][0] += c0 * t0; a2[0][1] += c0 * t1; a2[0][2] += c0 * t2; a2[0][3] += c0 * t3;
        a2[1][0] += c1 * t0; a2[1][1] += c1 * t1; a2[1][2] += c1 * t2; a2[1][3] += c1 * t3;
      }
      float e0 = expf(cs[i0]), e1 = expf(cs[i0 + 1]);
#pragma unroll
      for (int ii = 0; ii < 2; ++ii) {
        const long r = rowbase + i0 + ii;
        const long zo = r * 4096 + h * 64 + p0;
        const unsigned short* xr = proj + r * PROJ_N + h * 64 + p0;
        float e = ii ? e1 : e0;
#pragma unroll
        for (int pp = 0; pp < 4; ++pp) {
          float y = a1[ii][pp] + e * a2[ii][pp];
          float xraw = bf2f(xr[pp]);
          float zz = bf2f(zio[zo + pp]);
          float sz = zz / (1.f + expf(-zz));
          zio[zo + pp] = f2bf((y + xraw * Dh) * sz);
        }
      }
    }
    __syncthreads();
    // rescale Xs in place by exp(cs63 - cs_j)
    {
      const int j = tid >> 3;
      const int p0 = (tid & 7) * 8;
      float f = expf(cs[63] - cs[j]);
#pragma unroll
      for (int q = 0; q < 8; ++q) Xs[j][p0 + q] *= f;
    }
    __syncthreads();
    // state update: st = exp(cs63)*st + Xs^T @ Bs
    {
      const float dec = expf(cs[63]);
      const int p0 = (tid >> 5) * 4;
      const int n0 = (tid & 31) * 4;
      float a[4][4] = {};
      for (int j = 0; j < 64; ++j) {
        float x0 = Xs[j][p0], x1 = Xs[j][p0 + 1], x2 = Xs[j][p0 + 2], x3 = Xs[j][p0 + 3];
        float b0 = Bs[j][n0], b1 = Bs[j][n0 + 1], b2 = Bs[j][n0 + 2], b3 = Bs[j][n0 + 3];
        a[0][0] += x0 * b0; a[0][1] += x0 * b1; a[0][2] += x0 * b2; a[0][3] += x0 * b3;
        a[1][0] += x1 * b0; a[1][1] += x1 * b1; a[1][2] += x1 * b2; a[1][3] += x1 * b3;
        a[2][0] += x2 * b0; a[2][1] += x2 * b1; a[2][2] += x2 * b2; a[2][3] += x2 * b3;
        a[3][0] += x3 * b0; a[3][1] += x3 * b1; a[3][2] += x3 * b2; a[3][3] += x3 * b3;
      }
#pragma unroll
      for (int pp = 0; pp < 4; ++pp)
#pragma unroll
        for (int nn = 0; nn < 4; ++nn)
          st[p0 + pp][n0 + nn] = dec * st[p0 + pp][n0 + nn] + a[pp][nn];
    }
    __syncthreads();
  }
}

// ---------- launch ----------
extern "C" void kernel_launch(void* const* d_in, const int* in_sizes, int n_in,
                              void* d_out, int out_size, void* d_ws, size_t ws_size,
                              hipStream_t stream) {
  const float* x    = (const float*)d_in[0];
  const float* w1   = (const float*)d_in[1]; // 8192 x 2048
  const float* cw   = (const float*)d_in[2]; // 4096 x 4
  const float* cb   = (const float*)d_in[3]; // 4096
  const float* w2   = (const float*)d_in[4]; // 4416 x 4096
  const float* dtw  = (const float*)d_in[5]; // 64 x 64
  const float* dtb  = (const float*)d_in[6]; // 64
  const float* Alog = (const float*)d_in[7]; // 64
  const float* Dv   = (const float*)d_in[8]; // 64
  const float* w3   = (const float*)d_in[9]; // 2048 x 4096
  float* out = (float*)d_out;

  // per-pass scratch: CR*(4096*2 [xc/z] + 4416*2 [proj] + 64*4 [dt]) = CR*17280 B
  int CR;
  if (ws_size >= (size_t)8192 * 17280)      CR = 8192;
  else if (ws_size >= (size_t)4096 * 17280) CR = 4096;
  else return;  // diagnostic: error == 8.69e-2 means ws too small

  char* w = (char*)d_ws;
  const size_t S1 = (size_t)CR * 4096 * 2;
  const size_t S2 = (size_t)CR * PROJ_N * 2;
  unsigned short* xc   = (unsigned short*)(w);       // conv out   [0, S1)
  unsigned short* xp   = (unsigned short*)(w + S1);  // pre-conv   (inside proj region)
  unsigned short* proj = (unsigned short*)(w + S1);  // x_proj out — over xp (dead)
  unsigned short* z    = (unsigned short*)(w);       // z branch — over xc (dead)
  float* dtf           = (float*)(w + S1 + S2);

  for (int r0 = 0; r0 < 8192; r0 += CR) {
    const float* xr = x + (size_t)r0 * DMODEL;
    // 1) in_proj x-half -> xp (A fp32, out bf16)
    dim3 g1(DINNER / 128, CR / 128);
    gemm_nt<true, true><<<g1, 256, 0, stream>>>(xr, w1, xp, DMODEL, DINNER, DINNER);
    // 2) conv + silu -> xc
    conv_silu_kernel<<<((long)CR * DINNER) / 256, 256, 0, stream>>>(xp, cw, cb, xc, (long)CR * DINNER);
    // 3) x_proj -> proj (A bf16, out bf16; overwrites xp region)
    dim3 g2((PROJ_N + 127) / 128, CR / 128);
    gemm_nt<false, true><<<g2, 256, 0, stream>>>(xc, w2, proj, DINNER, PROJ_N, PROJ_N);
    // 4) dt
    dt_kernel<<<((long)CR * NHEADS) / 256, 256, 0, stream>>>(proj, dtw, dtb, dtf, (long)CR * NHEADS);
    // 5) in_proj z-half -> z (A fp32, out bf16; overwrites xc region)
    gemm_nt<true, true><<<g1, 256, 0, stream>>>(xr, w1 + (size_t)DINNER * DMODEL, z, DMODEL, DINNER, DINNER);
    // 6) SSD + gate, in place over z
    ssd_gate_kernel<<<(CR / LSEQ) * NHEADS, 512, 0, stream>>>(proj, dtf, Alog, Dv, z);
    // 7) out_proj -> d_out (A bf16, out fp32)
    dim3 g3(DMODEL / 128, CR / 128);
    gemm_nt<false, false><<<g3, 256, 0, stream>>>(z, w3, out + (size_t)r0 * DMODEL, DINNER, DMODEL, DMODEL);
  }
}